// Round 1
// baseline (11.039 us; speedup 1.0000x reference)
//
#include <hip/hip_runtime.h>

#define POOLN 7
#define BINS 49
#define ALPHA 16
#define Hd 160
#define Wd 160
#define Cd (BINS * ALPHA)
#define NROI 512

__global__ __launch_bounds__(256) void psroi_align_kernel(
    const float* __restrict__ img,
    const float* __restrict__ rois,
    float* __restrict__ out)
{
    const int total = NROI * BINS * ALPHA;
    int gid = blockIdx.x * blockDim.x + threadIdx.x;
    if (gid >= total) return;

    const int a = gid & (ALPHA - 1);
    const int k = (gid >> 4) % BINS;       // bin index, out layout = r*784 + k*16 + a
    const int r = gid / (BINS * ALPHA);

    // ROI box
    const float4 roi = reinterpret_cast<const float4*>(rois)[r];
    const float xmin = roi.x, ymin = roi.y, xmax = roi.z, ymax = roi.w;
    const float step_y = (ymax - ymin) / 7.0f;
    const float step_x = (xmax - xmin) / 7.0f;

    // NOTE: bx = k // 7 is the X direction, by = k % 7 is Y (per reference)
    const float bx = (float)(k / POOLN);
    const float by = (float)(k % POOLN);

    const float y1 = ymin + by * step_y;
    const float y2 = y1 + step_y;
    const float x1 = xmin + bx * step_x;
    const float x2 = x1 + step_x;

    float yy[2];
    float xx[2];
    yy[0] = y1 * (float)(Hd - 1);
    yy[1] = y2 * (float)(Hd - 1);
    xx[0] = x1 * (float)(Wd - 1);
    xx[1] = x2 * (float)(Wd - 1);

    const float* __restrict__ chan = img + k * ALPHA + a;

    float maxv;
    bool first = true;
    #pragma unroll
    for (int i = 0; i < 2; ++i) {
        const float y = yy[i];
        const bool vy = (y >= 0.0f) && (y <= (float)(Hd - 1));
        const float y0f = floorf(y);
        const float ly = y - y0f;
        const int y0 = (int)fminf(fmaxf(y0f, 0.0f), (float)(Hd - 1));
        const int y1i = (int)fminf(fmaxf(ceilf(y), 0.0f), (float)(Hd - 1));
        #pragma unroll
        for (int j = 0; j < 2; ++j) {
            const float x = xx[j];
            const bool vx = (x >= 0.0f) && (x <= (float)(Wd - 1));
            const float x0f = floorf(x);
            const float lx = x - x0f;
            const int x0 = (int)fminf(fmaxf(x0f, 0.0f), (float)(Wd - 1));
            const int x1i = (int)fminf(fmaxf(ceilf(x), 0.0f), (float)(Wd - 1));

            const float v00 = chan[(y0 * Wd + x0) * Cd];
            const float v01 = chan[(y0 * Wd + x1i) * Cd];
            const float v10 = chan[(y1i * Wd + x0) * Cd];
            const float v11 = chan[(y1i * Wd + x1i) * Cd];

            const float top = v00 + (v01 - v00) * lx;
            const float bot = v10 + (v11 - v10) * lx;
            float val = top + (bot - top) * ly;
            val = (vy && vx) ? val : 0.0f;

            maxv = first ? val : fmaxf(maxv, val);
            first = false;
        }
    }

    out[gid] = maxv;
}

extern "C" void kernel_launch(void* const* d_in, const int* in_sizes, int n_in,
                              void* d_out, int out_size, void* d_ws, size_t ws_size,
                              hipStream_t stream)
{
    const float* img = (const float*)d_in[0];
    const float* rois = (const float*)d_in[1];
    float* out = (float*)d_out;

    const int total = NROI * BINS * ALPHA;   // 401408
    const int block = 256;
    const int grid = (total + block - 1) / block;  // 1568
    psroi_align_kernel<<<grid, block, 0, stream>>>(img, rois, out);
}

// Round 2
// 10.647 us; speedup vs baseline: 1.0368x; 1.0368x over previous
//
#include <hip/hip_runtime.h>

#define POOLN 7
#define BINS 49
#define ALPHA 16
#define Hd 160
#define Wd 160
#define Cd (BINS * ALPHA)   // 784
#define C4 (Cd / 4)         // 196 float4s per (y,x) pixel
#define NROI 512

__global__ __launch_bounds__(256) void psroi_align_kernel(
    const float4* __restrict__ img4,
    const float* __restrict__ rois,
    float4* __restrict__ out4)
{
    const int total = NROI * BINS * 4;   // 100352 threads, one float4 (4 channels) each
    int gid = blockIdx.x * blockDim.x + threadIdx.x;
    if (gid >= total) return;

    const int a4 = gid & 3;              // which float4 of the 16-channel group
    const int k  = (gid >> 2) % BINS;    // bin index
    const int r  = gid / (BINS * 4);     // roi index

    const float4 roi = reinterpret_cast<const float4*>(rois)[r];
    const float xmin = roi.x, ymin = roi.y, xmax = roi.z, ymax = roi.w;
    const float step_y = (ymax - ymin) / 7.0f;
    const float step_x = (xmax - xmin) / 7.0f;

    // bx = k // 7 is the X direction, by = k % 7 is Y (per reference)
    const float bx = (float)(k / POOLN);
    const float by = (float)(k % POOLN);

    float yy[2], xx[2];
    const float y1 = ymin + by * step_y;
    const float x1 = xmin + bx * step_x;
    yy[0] = y1 * (float)(Hd - 1);
    yy[1] = (y1 + step_y) * (float)(Hd - 1);
    xx[0] = x1 * (float)(Wd - 1);
    xx[1] = (x1 + step_x) * (float)(Wd - 1);

    // channel base: float4 index = (y*W + x)*C4 + k*4 + a4
    const float4* __restrict__ chan = img4 + k * 4 + a4;

    float4 maxv = make_float4(-3.4e38f, -3.4e38f, -3.4e38f, -3.4e38f);

    #pragma unroll
    for (int i = 0; i < 2; ++i) {
        const float y = yy[i];
        const bool vy = (y >= 0.0f) && (y <= (float)(Hd - 1));
        const float y0f = floorf(y);
        const float ly = y - y0f;
        const int y0  = (int)fminf(fmaxf(y0f, 0.0f), (float)(Hd - 1));
        const int y1i = (int)fminf(fmaxf(ceilf(y), 0.0f), (float)(Hd - 1));
        #pragma unroll
        for (int j = 0; j < 2; ++j) {
            const float x = xx[j];
            const bool vx = (x >= 0.0f) && (x <= (float)(Wd - 1));
            const float x0f = floorf(x);
            const float lx = x - x0f;
            const int x0  = (int)fminf(fmaxf(x0f, 0.0f), (float)(Wd - 1));
            const int x1i = (int)fminf(fmaxf(ceilf(x), 0.0f), (float)(Wd - 1));

            const float4 v00 = chan[(y0  * Wd + x0 ) * C4];
            const float4 v01 = chan[(y0  * Wd + x1i) * C4];
            const float4 v10 = chan[(y1i * Wd + x0 ) * C4];
            const float4 v11 = chan[(y1i * Wd + x1i) * C4];

            float4 val;
            {
                const float tx = v00.x + (v01.x - v00.x) * lx;
                const float bxv = v10.x + (v11.x - v10.x) * lx;
                val.x = tx + (bxv - tx) * ly;
            }
            {
                const float tx = v00.y + (v01.y - v00.y) * lx;
                const float bxv = v10.y + (v11.y - v10.y) * lx;
                val.y = tx + (bxv - tx) * ly;
            }
            {
                const float tx = v00.z + (v01.z - v00.z) * lx;
                const float bxv = v10.z + (v11.z - v10.z) * lx;
                val.z = tx + (bxv - tx) * ly;
            }
            {
                const float tx = v00.w + (v01.w - v00.w) * lx;
                const float bxv = v10.w + (v11.w - v10.w) * lx;
                val.w = tx + (bxv - tx) * ly;
            }

            const bool valid = vy && vx;
            val.x = valid ? val.x : 0.0f;
            val.y = valid ? val.y : 0.0f;
            val.z = valid ? val.z : 0.0f;
            val.w = valid ? val.w : 0.0f;

            maxv.x = fmaxf(maxv.x, val.x);
            maxv.y = fmaxf(maxv.y, val.y);
            maxv.z = fmaxf(maxv.z, val.z);
            maxv.w = fmaxf(maxv.w, val.w);
        }
    }

    out4[gid] = maxv;
}

extern "C" void kernel_launch(void* const* d_in, const int* in_sizes, int n_in,
                              void* d_out, int out_size, void* d_ws, size_t ws_size,
                              hipStream_t stream)
{
    const float4* img4 = (const float4*)d_in[0];
    const float* rois = (const float*)d_in[1];
    float4* out4 = (float4*)d_out;

    const int total = NROI * BINS * 4;   // 100352
    const int block = 256;
    const int grid = (total + block - 1) / block;  // 392
    psroi_align_kernel<<<grid, block, 0, stream>>>(img4, rois, out4);
}

// Round 3
// 10.547 us; speedup vs baseline: 1.0467x; 1.0095x over previous
//
#include <hip/hip_runtime.h>

#define POOLN 7
#define BINS 49
#define ALPHA 16
#define Hd 160
#define Wd 160
#define Cd (BINS * ALPHA)   // 784
#define C4 (Cd / 4)         // 196 float4s per (y,x) pixel
#define NROI 512

__global__ __launch_bounds__(64) void psroi_align_kernel(
    const float4* __restrict__ img4,
    const float* __restrict__ rois,
    float4* __restrict__ out4)
{
    // total = 512*49*4 = 100352 threads = 1568 blocks * 64
    const int gid = blockIdx.x * 64 + threadIdx.x;

    const int a4 = gid & 3;              // which float4 of the 16-channel group
    const int k  = (gid >> 2) % BINS;    // bin index
    const int r  = gid / (BINS * 4);     // roi index

    const float4 roi = reinterpret_cast<const float4*>(rois)[r];
    const float xmin = roi.x, ymin = roi.y, xmax = roi.z, ymax = roi.w;
    const float step_y = (ymax - ymin) / 7.0f;
    const float step_x = (xmax - xmin) / 7.0f;

    // bx = k // 7 is the X direction, by = k % 7 is Y (per reference)
    const float bx = (float)(k / POOLN);
    const float by = (float)(k % POOLN);

    float yy[2], xx[2];
    const float y1 = ymin + by * step_y;
    const float x1 = xmin + bx * step_x;
    yy[0] = y1 * (float)(Hd - 1);
    yy[1] = (y1 + step_y) * (float)(Hd - 1);
    xx[0] = x1 * (float)(Wd - 1);
    xx[1] = (x1 + step_x) * (float)(Wd - 1);

    // channel base: float4 index = (y*W + x)*C4 + k*4 + a4
    const float4* __restrict__ chan = img4 + k * 4 + a4;

    float4 maxv = make_float4(-3.4e38f, -3.4e38f, -3.4e38f, -3.4e38f);

    #pragma unroll
    for (int i = 0; i < 2; ++i) {
        const float y = yy[i];
        const bool vy = (y >= 0.0f) && (y <= (float)(Hd - 1));
        const float y0f = floorf(y);
        const float ly = y - y0f;
        const int y0  = (int)fminf(fmaxf(y0f, 0.0f), (float)(Hd - 1));
        const int y1i = (int)fminf(fmaxf(ceilf(y), 0.0f), (float)(Hd - 1));
        #pragma unroll
        for (int j = 0; j < 2; ++j) {
            const float x = xx[j];
            const bool vx = (x >= 0.0f) && (x <= (float)(Wd - 1));
            const float x0f = floorf(x);
            const float lx = x - x0f;
            const int x0  = (int)fminf(fmaxf(x0f, 0.0f), (float)(Wd - 1));
            const int x1i = (int)fminf(fmaxf(ceilf(x), 0.0f), (float)(Wd - 1));

            const float4 v00 = chan[(y0  * Wd + x0 ) * C4];
            const float4 v01 = chan[(y0  * Wd + x1i) * C4];
            const float4 v10 = chan[(y1i * Wd + x0 ) * C4];
            const float4 v11 = chan[(y1i * Wd + x1i) * C4];

            float4 val;
            {
                const float t = v00.x + (v01.x - v00.x) * lx;
                const float b = v10.x + (v11.x - v10.x) * lx;
                val.x = t + (b - t) * ly;
            }
            {
                const float t = v00.y + (v01.y - v00.y) * lx;
                const float b = v10.y + (v11.y - v10.y) * lx;
                val.y = t + (b - t) * ly;
            }
            {
                const float t = v00.z + (v01.z - v00.z) * lx;
                const float b = v10.z + (v11.z - v10.z) * lx;
                val.z = t + (b - t) * ly;
            }
            {
                const float t = v00.w + (v01.w - v00.w) * lx;
                const float b = v10.w + (v11.w - v10.w) * lx;
                val.w = t + (b - t) * ly;
            }

            const bool valid = vy && vx;
            val.x = valid ? val.x : 0.0f;
            val.y = valid ? val.y : 0.0f;
            val.z = valid ? val.z : 0.0f;
            val.w = valid ? val.w : 0.0f;

            maxv.x = fmaxf(maxv.x, val.x);
            maxv.y = fmaxf(maxv.y, val.y);
            maxv.z = fmaxf(maxv.z, val.z);
            maxv.w = fmaxf(maxv.w, val.w);
        }
    }

    out4[gid] = maxv;
}

extern "C" void kernel_launch(void* const* d_in, const int* in_sizes, int n_in,
                              void* d_out, int out_size, void* d_ws, size_t ws_size,
                              hipStream_t stream)
{
    const float4* img4 = (const float4*)d_in[0];
    const float* rois = (const float*)d_in[1];
    float4* out4 = (float4*)d_out;

    const int total = NROI * BINS * 4;   // 100352
    const int block = 64;
    const int grid = total / block;      // 1568, exact
    psroi_align_kernel<<<grid, block, 0, stream>>>(img4, rois, out4);
}